// Round 3
// baseline (815.940 us; speedup 1.0000x reference)
//
#include <hip/hip_runtime.h>
#include <hip/hip_bf16.h>

// dims (fixed): T=4, B=1024, WH=WW=8, C=256, NH=8, HD=32
// tokens per timestep G = B*64 = 65536 ; plane = G*256 = 16777216 elements
static constexpr int  G     = 65536;
static constexpr long PLANE = 16777216L;

using bf16x8 = __attribute__((ext_vector_type(8))) short;
using f32x4  = __attribute__((ext_vector_type(4))) float;

__device__ __forceinline__ float bfh(unsigned short u) {
    union { unsigned u32; float f; } c; c.u32 = ((unsigned)u) << 16; return c.f;
}

// ---------------- prep: WqF fragment layout + WkT/WpT transpose + flag -------
// WqF[chunk][ntile][hi][c][j] = bf16(Wq[ntile*16+c][chunk*32+hi*8+j])
// => per (chunk,ntile) a wave's 64 lanes (lane = hi*16+c) each read 16 B
//    contiguous (j=0..7), i.e. one coalesced 1 KiB load = one B-fragment.
__global__ void prep_kernel(const float* __restrict__ Wq, const float* __restrict__ Wk,
                            const float* __restrict__ Wp,
                            __hip_bfloat16* __restrict__ WqF, __hip_bfloat16* __restrict__ WkT,
                            float* __restrict__ WpT, unsigned* __restrict__ flag)
{
    int c = blockIdx.x;      // input channel (row of transposed)
    int j = threadIdx.x;     // output channel
    int idx = c * 256 + j;
    WkT[idx] = __float2bfloat16(Wk[j * 256 + c]);
    WpT[idx] = Wp[j * 256 + c];
    // fragment-ordered Wq
    int jj = idx & 7, cc = (idx >> 3) & 15, hi = (idx >> 7) & 3,
        ntile = (idx >> 9) & 15, chunk = (idx >> 13) & 7;
    int n = ntile * 16 + cc;
    int k = chunk * 32 + hi * 8 + jj;
    WqF[idx] = __float2bfloat16(Wq[n * 256 + k]);
    if (idx == 0) *flag = 0u;
}

// depth-2 pipelined sparse row-gather over one 64-bit mask word (rare k-path)
__device__ __forceinline__ void gather_word(unsigned long long mm, int j, int lane,
                                            const __hip_bfloat16* __restrict__ WT,
                                            float& q0, float& q1, float& q2, float& q3)
{
    if (!mm) return;
    int b = __ffsll(mm) - 1; mm &= (mm - 1);
    ushort4 w = *((const ushort4*)(WT + (4 * b + j) * 256 + 4 * lane));
    while (mm) {
        int b2 = __ffsll(mm) - 1; mm &= (mm - 1);
        ushort4 w2 = *((const ushort4*)(WT + (4 * b2 + j) * 256 + 4 * lane));
        q0 += bfh(w.x); q1 += bfh(w.y); q2 += bfh(w.z); q3 += bfh(w.w);
        w = w2;
    }
    q0 += bfh(w.x); q1 += bfh(w.y); q2 += bfh(w.z); q3 += bfh(w.w);
}

// ---------------- fused: LIF(x) -> MFMA q-GEMM -> LIF -> att -> AM masks -----
// Wave = one 16-row M-tile = 4 tokens x 4 timesteps (A-row = 4*tk + t).
// Input-spike ballots are the A-matrix:
//   sm[t][j] bit L = spike(channel 4L+j, timestep t)   (word = k&3, bit = k>>2)
// A-frag (16x16x32, k-map kappa(hi,j)=hi*8+j): lane owns row lane&15; element j
//   of chunk ch = bit (ch*8 + hi*2 + (j>>2)) of its designated token/t's word j&3.
// Any consistent kappa is valid: A and B share the same lane->k map, so a
// permutation of k leaves the dot product unchanged.
// C/D (m89-verified): col = lane&15 (q channel within ntile),
//   row = (lane>>4)*4 + reg  => token = lane>>4, t = reg: q-LIF chain is
//   register-local; per-(token,t) q-spike count = 16-bit ballot slices.
__global__ __launch_bounds__(256) void lif_qk_kernel(
    const float* __restrict__ x,
    unsigned* __restrict__ AM,
    const __hip_bfloat16* __restrict__ WqF,
    const __hip_bfloat16* __restrict__ WkT,
    const float* __restrict__ pos,
    unsigned* __restrict__ flag)
{
    int lane  = threadIdx.x & 63;
    int wv    = threadIdx.x >> 6;
    int wid   = blockIdx.x * 4 + wv;     // 16384 waves, 4 tokens each
    int hi    = lane >> 4;               // k-group (A/B), token index (C/D)
    int myrow = lane & 15;               // owned A-row: token myrow>>2, t myrow&3
    int tksh  = lane & 48;               // (lane>>4)*16 : ballot slice shift

    // ---- phase 1: input LIF masks for the wave's 4 tokens; distribute the
    //      mask words to their A-row owner lanes (wave-uniform ballots).
    unsigned long long mm0 = 0, mm1 = 0, mm2 = 0, mm3 = 0;
    #pragma unroll
    for (int tk = 0; tk < 4; ++tk) {
        int g = wid * 4 + tk;
        float4 X0 = ((const float4*)(x + 0L * PLANE + (long)g * 256))[lane];
        float4 X1 = ((const float4*)(x + 1L * PLANE + (long)g * 256))[lane];
        float4 X2 = ((const float4*)(x + 2L * PLANE + (long)g * 256))[lane];
        float4 X3 = ((const float4*)(x + 3L * PLANE + (long)g * 256))[lane];
        float4 v = make_float4(0.f, 0.f, 0.f, 0.f);
        #pragma unroll
        for (int t = 0; t < 4; ++t) {
            float4 X = (t == 0) ? X0 : (t == 1) ? X1 : (t == 2) ? X2 : X3;
            v.x = v.x + (X.x - v.x) * 0.5f; bool s0 = (v.x - 1.0f) >= 0.0f; if (s0) v.x = 0.f;
            v.y = v.y + (X.y - v.y) * 0.5f; bool s1 = (v.y - 1.0f) >= 0.0f; if (s1) v.y = 0.f;
            v.z = v.z + (X.z - v.z) * 0.5f; bool s2 = (v.z - 1.0f) >= 0.0f; if (s2) v.z = 0.f;
            v.w = v.w + (X.w - v.w) * 0.5f; bool s3 = (v.w - 1.0f) >= 0.0f; if (s3) v.w = 0.f;
            unsigned long long b0 = __ballot(s0);
            unsigned long long b1 = __ballot(s1);
            unsigned long long b2 = __ballot(s2);
            unsigned long long b3 = __ballot(s3);
            bool sel = (myrow == tk * 4 + t);
            if (sel) { mm0 = b0; mm1 = b1; mm2 = b2; mm3 = b3; }
        }
    }

    // ---- phase 2: build A fragments from mask bits (pure VALU)
    bf16x8 af[8];
    #pragma unroll
    for (int ch = 0; ch < 8; ++ch) {
        int bb = ch * 8 + hi * 2;
        unsigned w0 = (unsigned)(mm0 >> bb);
        unsigned w1 = (unsigned)(mm1 >> bb);
        unsigned w2 = (unsigned)(mm2 >> bb);
        unsigned w3 = (unsigned)(mm3 >> bb);
        bf16x8 a;
        a[0] = (w0 & 1u) ? (short)0x3F80 : (short)0;
        a[1] = (w1 & 1u) ? (short)0x3F80 : (short)0;
        a[2] = (w2 & 1u) ? (short)0x3F80 : (short)0;
        a[3] = (w3 & 1u) ? (short)0x3F80 : (short)0;
        a[4] = ((w0 >> 1) & 1u) ? (short)0x3F80 : (short)0;
        a[5] = ((w1 >> 1) & 1u) ? (short)0x3F80 : (short)0;
        a[6] = ((w2 >> 1) & 1u) ? (short)0x3F80 : (short)0;
        a[7] = ((w3 >> 1) & 1u) ? (short)0x3F80 : (short)0;
        af[ch] = a;
    }

    // ---- phase 3: q GEMM (8 chunks x 16 ntiles), q-LIF, att-LIF per head
    const char* wqf = (const char*)WqF;
    unsigned attw = 0u;                  // bit h*4+t: att spike of (token hi, head h)
    for (int h = 0; h < 8; ++h) {
        unsigned long long bal[2][4];
        #pragma unroll
        for (int sub = 0; sub < 2; ++sub) {
            int nt = h * 2 + sub;
            f32x4 acc = {0.f, 0.f, 0.f, 0.f};
            #pragma unroll
            for (int ch = 0; ch < 8; ++ch) {
                bf16x8 b = *(const bf16x8*)(wqf + (ch << 14) + (nt << 10) + (lane << 4));
                acc = __builtin_amdgcn_mfma_f32_16x16x32_bf16(af[ch], b, acc, 0, 0, 0);
            }
            float vq = 0.f;
            #pragma unroll
            for (int t = 0; t < 4; ++t) {
                vq = vq + (acc[t] - vq) * 0.5f;
                bool sp = (vq - 1.0f) >= 0.0f; if (sp) vq = 0.f;
                bal[sub][t] = __ballot(sp);
            }
        }
        float va = 0.f;
        #pragma unroll
        for (int t = 0; t < 4; ++t) {
            int cnt = __popc((unsigned)(bal[0][t] >> tksh) & 0xFFFFu)
                    + __popc((unsigned)(bal[1][t] >> tksh) & 0xFFFFu);
            va = va + ((float)cnt - va) * 0.5f;
            bool a = (va - 1.0f) >= 0.0f; if (a) va = 0.f;
            attw |= (a ? 1u : 0u) << (h * 4 + t);
        }
    }

    bool anyatt = (__ballot(attw != 0u) != 0ull);
    if (!anyatt) {
        if (lane < 32) {
            int t = lane >> 3, wd = lane & 7;
            #pragma unroll
            for (int tk = 0; tk < 4; ++tk)
                AM[((long)t * G + (wid * 4 + tk)) * 8 + wd] = 0u;
        }
    } else {
        // rare: full k path (wave-uniform), token by token
        if (lane == 0) atomicOr(flag, 1u);
        for (int tk = 0; tk < 4; ++tk) {
            int g  = wid * 4 + tk;
            int hw = g & 63;
            unsigned attw_tk = __shfl(attw, tk * 16);
            // recompute this token's input-spike masks (identical arithmetic)
            unsigned long long sm[4][4];
            {
                float4 v = make_float4(0.f, 0.f, 0.f, 0.f);
                #pragma unroll
                for (int t = 0; t < 4; ++t) {
                    float4 X = ((const float4*)(x + (long)t * PLANE + (long)g * 256))[lane];
                    v.x = v.x + (X.x - v.x) * 0.5f; bool s0 = (v.x - 1.0f) >= 0.0f; if (s0) v.x = 0.f;
                    v.y = v.y + (X.y - v.y) * 0.5f; bool s1 = (v.y - 1.0f) >= 0.0f; if (s1) v.y = 0.f;
                    v.z = v.z + (X.z - v.z) * 0.5f; bool s2 = (v.z - 1.0f) >= 0.0f; if (s2) v.z = 0.f;
                    v.w = v.w + (X.w - v.w) * 0.5f; bool s3 = (v.w - 1.0f) >= 0.0f; if (s3) v.w = 0.f;
                    sm[t][0] = __ballot(s0);
                    sm[t][1] = __ballot(s1);
                    sm[t][2] = __ballot(s2);
                    sm[t][3] = __ballot(s3);
                }
            }
            unsigned attb = (attw_tk >> ((lane >> 3) * 4)) & 0xFu;
            float4 vk = make_float4(0.f, 0.f, 0.f, 0.f);
            #pragma unroll
            for (int t = 0; t < 4; ++t) {
                float k0 = 0.f, k1 = 0.f, k2 = 0.f, k3 = 0.f;
                #pragma unroll
                for (int j = 0; j < 4; ++j)
                    gather_word(sm[t][j], j, lane, WkT, k0, k1, k2, k3);
                float4 pp = ((const float4*)(pos + t * 16384 + hw * 256))[lane];
                k0 += pp.x; k1 += pp.y; k2 += pp.z; k3 += pp.w;

                vk.x = vk.x + (k0 - vk.x) * 0.5f; bool t0 = (vk.x - 1.0f) >= 0.0f; if (t0) vk.x = 0.f;
                vk.y = vk.y + (k1 - vk.y) * 0.5f; bool t1 = (vk.y - 1.0f) >= 0.0f; if (t1) vk.y = 0.f;
                vk.z = vk.z + (k2 - vk.z) * 0.5f; bool t2 = (vk.z - 1.0f) >= 0.0f; if (t2) vk.z = 0.f;
                vk.w = vk.w + (k3 - vk.w) * 0.5f; bool t3 = (vk.w - 1.0f) >= 0.0f; if (t3) vk.w = 0.f;

                bool at = ((attb >> t) & 1u) != 0u;
                unsigned long long bb[4];
                bb[0] = __ballot(t0 && at);
                bb[1] = __ballot(t1 && at);
                bb[2] = __ballot(t2 && at);
                bb[3] = __ballot(t3 && at);
                if (lane < 8) {
                    unsigned wdv = 0u;
                    #pragma unroll
                    for (int hd = 0; hd < 32; ++hd) {
                        int ls = lane * 8 + (hd >> 2);
                        wdv |= (unsigned)((bb[hd & 3] >> ls) & 1ull) << hd;
                    }
                    AM[((long)t * G + g) * 8 + lane] = wdv;
                }
            }
        }
    }
}

// ---------------- out: flag-gated pure streaming stores ----------------
// Common case (flag==0): y = bp broadcast, attn_out = 0; no loads in the loop.
// attn_out ≡ 0 proved: x2 in {0,1}, v'=(v+x)/2 < 1 strictly (exact dyadic fp32).
// Rare case: per-row AM gather (permutation verified R0).
__global__ __launch_bounds__(256) void out_kernel(
    const unsigned* __restrict__ AM,
    const float* __restrict__ WpT,
    const float* __restrict__ bp,
    const unsigned* __restrict__ flag,
    float* __restrict__ y,
    float* __restrict__ attn_out)
{
    int lane = threadIdx.x & 63;
    int wv   = threadIdx.x >> 6;
    long wave = (long)blockIdx.x * 4 + wv;      // 0..8191 ; 32 rows/wave
    int  nh   = lane >> 3;

    float4 base = ((const float4*)bp)[lane];
    const float4 z = make_float4(0.f, 0.f, 0.f, 0.f);
    long row0 = wave * 32;

    if (*flag == 0u) {
        float4* yp = (float4*)y        + row0 * 64 + lane;
        float4* ap = (float4*)attn_out + row0 * 64 + lane;
        #pragma unroll 8
        for (int r = 0; r < 32; ++r) yp[r * 64] = base;
        #pragma unroll 8
        for (int r = 0; r < 32; ++r) ap[r * 64] = z;
        return;
    }

    // rare path
    int t2  = (int)(row0 >> 16);
    int b2  = (int)(row0 >> 6) & 1023;
    int hw2 = (int)row0 & 63;
    int srow = (b2 * 4 + (nh >> 1)) * 64 + (nh & 1) * 32 + t2 * 8 + (hw2 >> 3);
    unsigned W = AM[(long)srow * 8 + (hw2 & 7)];

    for (int r = 0; r < 32; ++r) {
        long row = row0 + r;
        unsigned Wn = 0u;
        if (r < 31) {
            long rown = row + 1;
            int t2n  = (int)(rown >> 16);
            int b2n  = (int)(rown >> 6) & 1023;
            int hw2n = (int)rown & 63;
            int srn  = (b2n * 4 + (nh >> 1)) * 64 + (nh & 1) * 32 + t2n * 8 + (hw2n >> 3);
            Wn = AM[(long)srn * 8 + (hw2n & 7)];
        }
        float4 val = base;
        if (__ballot(W != 0u) != 0ull) {
            #pragma unroll 1
            for (int n2 = 0; n2 < 8; ++n2) {
                unsigned Wx = __shfl(W, n2 * 8);
                while (Wx) {
                    int hd = __ffs(Wx) - 1;
                    Wx &= (Wx - 1);
                    float4 wl = ((const float4*)(WpT + (n2 * 32 + hd) * 256))[lane];
                    val.x += wl.x; val.y += wl.y; val.z += wl.z; val.w += wl.w;
                }
            }
        }
        ((float4*)y)[row * 64 + lane]        = val;
        ((float4*)attn_out)[row * 64 + lane] = z;
        W = Wn;
    }
}

extern "C" void kernel_launch(void* const* d_in, const int* in_sizes, int n_in,
                              void* d_out, int out_size, void* d_ws, size_t ws_size,
                              hipStream_t stream) {
    const float* x   = (const float*)d_in[0];
    const float* Wq  = (const float*)d_in[1];
    const float* Wk  = (const float*)d_in[2];
    const float* Wp  = (const float*)d_in[3];
    const float* bp  = (const float*)d_in[4];
    const float* pos = (const float*)d_in[5];

    float* y        = (float*)d_out;
    float* attn_out = y + 67108864L;

    char* ws = (char*)d_ws;
    unsigned*           AM   = (unsigned*)(ws);
    __hip_bfloat16*     WqF  = (__hip_bfloat16*)(ws + (8L << 20));
    __hip_bfloat16*     WkT  = (__hip_bfloat16*)(ws + (8L << 20) + (128L << 10));
    float*              WpT  = (float*)(ws + (8L << 20) + (256L << 10));
    unsigned*           flag = (unsigned*)(ws + (8L << 20) + (512L << 10));

    prep_kernel<<<256, 256, 0, stream>>>(Wq, Wk, Wp, WqF, WkT, WpT, flag);
    lif_qk_kernel<<<4096, 256, 0, stream>>>(x, AM, WqF, WkT, pos, flag);
    out_kernel<<<2048, 256, 0, stream>>>(AM, WpT, bp, flag, y, attn_out);
}